// Round 1
// 82.248 us; speedup vs baseline: 1.0164x; 1.0164x over previous
//
#include <hip/hip_runtime.h>
#include <math.h>

// LSSL kernel: K[d,l] = Re sum_n (C*b_bar)[d,n] * a_bar[d,n]^l,  plus D passthrough.
//
// R2 structure: one block per (d, l-chunk), BLOCK=1024 threads split into NGROUP=4
// groups of LCOV=256 lanes. Each group handles NPER=16 of the 64 states over the
// same l-range (l = l0 + (tid&255) + j*256), so total instruction work is identical
// to R1 but the machine sees 16 waves/block (16-32 waves/CU vs R1's 8) — 2-4x the
// latency-hiding. Cross-group combine via padded LDS (row stride 9 floats, coprime
// with 32 banks -> conflict-free).
//
// Preamble (64 threads) does the bilinear discretization into LDS:
//   s_wa[n] = {w_re, w_im, aS_re, aS_im}   (aS = a^LCOV, the per-j step factor)
//   s_lt[n] = {log2|a|, arg(a)/2pi}
// Inner loop per n: p = w * a^(l0+lane) via 3 transcendentals ONCE, then step j
// with a 4-op complex multiply by a^LCOV (+1 acc add).

#define STATE_DIM 64
#define BLOCK 1024
#define LCOV 256                    // l-lanes per group (and j-stride)
#define NGROUP 4
#define NPER (STATE_DIM / NGROUP)   // 16 states per group
#define LT 8

__global__ __launch_bounds__(BLOCK) void lssl_kernel(
    const float* __restrict__ Lre, const float* __restrict__ Lim,
    const float* __restrict__ Bre, const float* __restrict__ Bim,
    const float* __restrict__ Cre, const float* __restrict__ Cim,
    const float* __restrict__ Dv,  const float* __restrict__ log_dt,
    float* __restrict__ out, int d_model, int L)
{
    const int d   = blockIdx.x;
    const int tid = threadIdx.x;
    const int lt  = tid & (LCOV - 1);   // lane within l-range
    const int g   = tid >> 8;           // n-group 0..3

    __shared__ float4 s_wa[STATE_DIM];  // w_re, w_im, aS_re, aS_im
    __shared__ float2 s_lt[STATE_DIM];  // log2|a|, arg(a)/(2*pi)
    __shared__ float  s_red[NGROUP - 1][LCOV][LT + 1];  // +1 pad: 9 coprime 32 -> no bank conflict

    if (tid < STATE_DIM) {
        const int n   = tid;
        const int idx = d * STATE_DIM + n;
        // lam = -softplus(Lre) + i*Lim
        float x      = Lre[idx];
        float sp     = fmaxf(x, 0.0f) + log1pf(expf(-fabsf(x)));
        float lam_re = -sp;
        float lam_im = Lim[idx];
        float dt     = expf(log_dt[d]);
        float hre    = 0.5f * dt * lam_re;
        float him    = 0.5f * dt * lam_im;
        float dre = 1.0f - hre, dim = -him;
        float inv = 1.0f / (dre * dre + dim * dim);
        float nre = 1.0f + hre, nim = him;
        float are = (nre * dre + nim * dim) * inv;   // a_bar
        float aim = (nim * dre - nre * dim) * inv;
        float idre = dre * inv, idim = -dim * inv;   // 1/denom
        float bre = Bre[idx], bim = Bim[idx];
        float bbre = dt * (idre * bre - idim * bim); // b_bar
        float bbim = dt * (idre * bim + idim * bre);
        float cre = Cre[idx], cim = Cim[idx];
        float wre = cre * bbre - cim * bbim;         // w = C * b_bar
        float wim = cre * bbim + cim * bbre;

        float r2    = are * are + aim * aim;
        float log2r = 0.5f * log2f(r2);
        float threv = atan2f(aim, are) * 0.15915494309189535f;  // arg(a)/2pi

        // step factor a^LCOV (j-stride is LCOV, independent of block size)
        float eS = __builtin_amdgcn_exp2f((float)LCOV * log2r);
        float tS = (float)LCOV * threv;
        tS -= floorf(tS);
        float aSre = eS * __builtin_amdgcn_cosf(tS);
        float aSim = eS * __builtin_amdgcn_sinf(tS);

        s_wa[n] = make_float4(wre, wim, aSre, aSim);
        s_lt[n] = make_float2(log2r, threv);
    }
    __syncthreads();

    const int l0  = blockIdx.y * (LCOV * LT);
    const float fl0 = (float)(l0 + lt);

    float acc[LT];
    #pragma unroll
    for (int j = 0; j < LT; ++j) acc[j] = 0.0f;

    const int nbase = g * NPER;
    #pragma unroll 4
    for (int nn = 0; nn < NPER; ++nn) {
        const int n = nbase + nn;
        float4 wa  = s_wa[n];
        float2 ltc = s_lt[n];
        // u = a^(l0+lt)
        float e = __builtin_amdgcn_exp2f(fl0 * ltc.x);
        float t = fl0 * ltc.y;
        t -= floorf(t);
        float s = __builtin_amdgcn_sinf(t);
        float c = __builtin_amdgcn_cosf(t);
        float ure = e * c, uim = e * s;
        // p = w * u
        float pre = wa.x * ure - wa.y * uim;
        float pim = wa.x * uim + wa.y * ure;
        acc[0] += pre;
        #pragma unroll
        for (int j = 1; j < LT; ++j) {
            // p *= a^LCOV
            float t0  = pre * wa.z;
            float t1  = pre * wa.w;
            float nr  = fmaf(-pim, wa.w, t0);
            float ni  = fmaf( pim, wa.z, t1);
            pre = nr; pim = ni;
            acc[j] += pre;
        }
    }

    // cross-group reduction: groups 1..3 park partials in LDS, group 0 combines+stores
    if (g != 0) {
        #pragma unroll
        for (int j = 0; j < LT; ++j) s_red[g - 1][lt][j] = acc[j];
    }
    __syncthreads();
    if (g == 0) {
        float* orow = out + (size_t)d * L;
        #pragma unroll
        for (int j = 0; j < LT; ++j) {
            float v = acc[j] + s_red[0][lt][j] + s_red[1][lt][j] + s_red[2][lt][j];
            int l = l0 + lt + j * LCOV;
            if (l < L) orow[l] = v;
        }
        if (tid == 0 && blockIdx.y == 0) {
            out[(size_t)d_model * L + d] = Dv[d];  // D output (tuple element 1)
        }
    }
}

extern "C" void kernel_launch(void* const* d_in, const int* in_sizes, int n_in,
                              void* d_out, int out_size, void* d_ws, size_t ws_size,
                              hipStream_t stream) {
    const float* Lre    = (const float*)d_in[0];
    const float* Lim    = (const float*)d_in[1];
    const float* Bre    = (const float*)d_in[2];
    const float* Bim    = (const float*)d_in[3];
    const float* Cre    = (const float*)d_in[4];
    const float* Cim    = (const float*)d_in[5];
    const float* Dv     = (const float*)d_in[6];
    const float* log_dt = (const float*)d_in[7];
    float* out = (float*)d_out;

    const int d_model = in_sizes[6];               // 512
    const int L       = out_size / d_model - 1;    // K is d_model*L, D is d_model

    const int chunk = LCOV * LT;                   // l-range covered per block (2048)
    dim3 grid(d_model, (L + chunk - 1) / chunk);
    lssl_kernel<<<grid, BLOCK, 0, stream>>>(Lre, Lim, Bre, Bim, Cre, Cim, Dv, log_dt,
                                            out, d_model, L);
}